// Round 1
// baseline (1268.981 us; speedup 1.0000x reference)
//
#include <hip/hip_runtime.h>
#include <hip/hip_bf16.h>

#define B_ROWS   4096
#define L_LABELS 100000
#define D_DIM    256
#define TOPK     5

#define BM 128
#define BN 128
#define BK 32
#define KPAD 40   // 32 + 8 pad: row stride 80 B -> conflict-free ds_read_b128

typedef __bf16 bf16x8 __attribute__((ext_vector_type(8)));
typedef __bf16 bf16x4 __attribute__((ext_vector_type(4)));
typedef float  f32x4  __attribute__((ext_vector_type(4)));

// ---------------------------------------------------------------------------
// Kernel 1: per-row threshold s_t = dot(P[b], Lab[t_b]) with bf16-rounded
// inputs (matches MFMA product rounding), and zero the per-row beat counters.
// One wave per row: 64 lanes x 4 elements = 256 = D_DIM.
// ---------------------------------------------------------------------------
__global__ void prep_kernel(const float* __restrict__ P,
                            const float* __restrict__ Lab,
                            const int*   __restrict__ labels,
                            float* __restrict__ s_t,
                            int*   __restrict__ counts) {
    int gwave = (blockIdx.x * blockDim.x + threadIdx.x) >> 6;
    int lane  = threadIdx.x & 63;
    if (gwave >= B_ROWS) return;
    int t = labels[gwave];
    const float4* p4 = (const float4*)(P + (size_t)gwave * D_DIM);
    const float4* l4 = (const float4*)(Lab + (size_t)t * D_DIM);
    float4 a = p4[lane];
    float4 b = l4[lane];
    float sum = 0.f;
    sum += (float)(__bf16)a.x * (float)(__bf16)b.x;
    sum += (float)(__bf16)a.y * (float)(__bf16)b.y;
    sum += (float)(__bf16)a.z * (float)(__bf16)b.z;
    sum += (float)(__bf16)a.w * (float)(__bf16)b.w;
    #pragma unroll
    for (int m = 1; m < 64; m <<= 1) sum += __shfl_xor(sum, m, 64);
    if (lane == 0) {
        s_t[gwave]   = sum;
        counts[gwave] = 0;
    }
}

// ---------------------------------------------------------------------------
// Kernel 2: tiled MFMA "count beats" GEMM.
// Block = 256 threads (4 waves, 2x2), tile 128 rows x 128 labels.
// Epilogue compares each dot against s_t[row] and atomically accumulates the
// number of labels beating the true label's similarity.
// ---------------------------------------------------------------------------
__global__ __launch_bounds__(256)
void count_kernel(const float* __restrict__ P,
                  const float* __restrict__ Lab,
                  const int*   __restrict__ labels,
                  const float* __restrict__ s_t,
                  int* __restrict__ counts) {
    __shared__ __align__(16) __bf16 As[BM][KPAD];
    __shared__ __align__(16) __bf16 Bs[BN][KPAD];

    const int Nbase = blockIdx.x * BN;
    const int Mbase = blockIdx.y * BM;
    const int tid  = threadIdx.x;
    const int lane = tid & 63;
    const int wave = tid >> 6;
    const int wm = wave >> 1;        // 0..1 : which 64-row half
    const int wn = wave & 1;         // 0..1 : which 64-label half
    const int quad = lane >> 4;      // 0..3
    const int c    = lane & 15;      // 0..15

    // staging assignment: thread -> (row 0..127, k-half 0/16)
    const int srow  = tid >> 1;
    const int skoff = (tid & 1) * 16;
    const int brow_g = min(Nbase + srow, L_LABELS - 1);  // clamp partial N tile

    f32x4 acc[4][4] = {};

    for (int Kb = 0; Kb < D_DIM; Kb += BK) {
        const float* gA = P   + (size_t)(Mbase + srow) * D_DIM + Kb + skoff;
        const float* gB = Lab + (size_t)brow_g        * D_DIM + Kb + skoff;
        #pragma unroll
        for (int i = 0; i < 4; ++i) {
            float4 va = *(const float4*)(gA + i * 4);
            float4 vb = *(const float4*)(gB + i * 4);
            *(bf16x4*)&As[srow][skoff + i * 4] =
                (bf16x4){(__bf16)va.x, (__bf16)va.y, (__bf16)va.z, (__bf16)va.w};
            *(bf16x4*)&Bs[srow][skoff + i * 4] =
                (bf16x4){(__bf16)vb.x, (__bf16)vb.y, (__bf16)vb.z, (__bf16)vb.w};
        }
        __syncthreads();

        bf16x8 af[4], bf[4];
        #pragma unroll
        for (int mi = 0; mi < 4; ++mi)
            af[mi] = *(const bf16x8*)&As[wm * 64 + mi * 16 + c][quad * 8];
        #pragma unroll
        for (int ni = 0; ni < 4; ++ni)
            bf[ni] = *(const bf16x8*)&Bs[wn * 64 + ni * 16 + c][quad * 8];

        #pragma unroll
        for (int mi = 0; mi < 4; ++mi)
            #pragma unroll
            for (int ni = 0; ni < 4; ++ni)
                acc[mi][ni] = __builtin_amdgcn_mfma_f32_16x16x32_bf16(
                    af[mi], bf[ni], acc[mi][ni], 0, 0, 0);
        __syncthreads();
    }

    // Epilogue: C/D layout col = lane&15, row = quad*4 + reg  [m89/m91]
    #pragma unroll
    for (int mi = 0; mi < 4; ++mi) {
        int rowb = Mbase + wm * 64 + mi * 16 + quad * 4;
        #pragma unroll
        for (int r = 0; r < 4; ++r) {
            int   row = rowb + r;
            float st  = s_t[row];
            int   t   = labels[row];
            int   cnt = 0;
            #pragma unroll
            for (int ni = 0; ni < 4; ++ni) {
                int   n = Nbase + wn * 64 + ni * 16 + c;
                float s = acc[mi][ni][r];
                bool beat = (n < L_LABELS) && (n != t) &&
                            (s > st || (s == st && n < t));
                cnt += beat ? 1 : 0;
            }
            cnt += __shfl_xor(cnt, 1, 64);
            cnt += __shfl_xor(cnt, 2, 64);
            cnt += __shfl_xor(cnt, 4, 64);
            cnt += __shfl_xor(cnt, 8, 64);
            if (c == 0 && cnt) atomicAdd(&counts[row], cnt);
        }
    }
}

// ---------------------------------------------------------------------------
// Kernel 3: accuracy = mean(counts[b] < TOPK)
// ---------------------------------------------------------------------------
__global__ void finalize_kernel(const int* __restrict__ counts,
                                float* __restrict__ out) {
    __shared__ int sdata[4];
    int tid = threadIdx.x;  // 256 threads
    int local = 0;
    for (int i = tid; i < B_ROWS; i += 256)
        local += (counts[i] < TOPK) ? 1 : 0;
    #pragma unroll
    for (int m = 1; m < 64; m <<= 1) local += __shfl_xor(local, m, 64);
    if ((tid & 63) == 0) sdata[tid >> 6] = local;
    __syncthreads();
    if (tid == 0)
        out[0] = (float)(sdata[0] + sdata[1] + sdata[2] + sdata[3]) /
                 (float)B_ROWS;
}

extern "C" void kernel_launch(void* const* d_in, const int* in_sizes, int n_in,
                              void* d_out, int out_size, void* d_ws, size_t ws_size,
                              hipStream_t stream) {
    const float* P      = (const float*)d_in[0];
    const float* Lab    = (const float*)d_in[1];
    const int*   labels = (const int*)d_in[2];
    float* out = (float*)d_out;

    float* s_t    = (float*)d_ws;
    int*   counts = (int*)((char*)d_ws + B_ROWS * sizeof(float));

    prep_kernel<<<dim3(B_ROWS / 4), 256, 0, stream>>>(P, Lab, labels, s_t, counts);

    dim3 grid((L_LABELS + BN - 1) / BN, B_ROWS / BM);  // 782 x 32
    count_kernel<<<grid, 256, 0, stream>>>(P, Lab, labels, s_t, counts);

    finalize_kernel<<<1, 256, 0, stream>>>(counts, out);
}

// Round 2
// 1047.650 us; speedup vs baseline: 1.2113x; 1.2113x over previous
//
#include <hip/hip_runtime.h>
#include <hip/hip_bf16.h>

#define B_ROWS   4096
#define L_LABELS 100000
#define L_PAD    100096   // 391 * 256, padded with zero rows
#define D_DIM    256
#define TOPK     5

typedef __bf16 bf16x8 __attribute__((ext_vector_type(8)));
typedef __bf16 bf16x4 __attribute__((ext_vector_type(4)));
typedef float  f32x4  __attribute__((ext_vector_type(4)));

// ---------------------------------------------------------------------------
// async global->LDS 16B DMA. LDS dest is wave-uniform base; HW adds lane*16.
// ---------------------------------------------------------------------------
__device__ __forceinline__ void async16(const void* g, void* l) {
    __builtin_amdgcn_global_load_lds(
        (const __attribute__((address_space(1))) unsigned int*)g,
        (__attribute__((address_space(3))) unsigned int*)l,
        16, 0, 0);
}

// ---------------------------------------------------------------------------
// fp32 -> bf16 converters (run every call; ws is re-poisoned each launch)
// ---------------------------------------------------------------------------
__global__ void convertP_kernel(const float* __restrict__ src,
                                __hip_bfloat16* __restrict__ dst) {
    size_t i = ((size_t)blockIdx.x * blockDim.x + threadIdx.x) * 8;
    float4 a = *(const float4*)(src + i);
    float4 b = *(const float4*)(src + i + 4);
    bf16x8 v = {(__bf16)a.x, (__bf16)a.y, (__bf16)a.z, (__bf16)a.w,
                (__bf16)b.x, (__bf16)b.y, (__bf16)b.z, (__bf16)b.w};
    *(bf16x8*)((__bf16*)dst + i) = v;
}

__global__ void convertL_kernel(const float* __restrict__ src,
                                __hip_bfloat16* __restrict__ dst) {
    size_t i = ((size_t)blockIdx.x * blockDim.x + threadIdx.x) * 8;
    bf16x8 v;
    if (i < (size_t)L_LABELS * D_DIM) {
        float4 a = *(const float4*)(src + i);
        float4 b = *(const float4*)(src + i + 4);
        v = (bf16x8){(__bf16)a.x, (__bf16)a.y, (__bf16)a.z, (__bf16)a.w,
                     (__bf16)b.x, (__bf16)b.y, (__bf16)b.z, (__bf16)b.w};
    } else {
        v = (bf16x8){(__bf16)0.f, (__bf16)0.f, (__bf16)0.f, (__bf16)0.f,
                     (__bf16)0.f, (__bf16)0.f, (__bf16)0.f, (__bf16)0.f};
    }
    *(bf16x8*)((__bf16*)dst + i) = v;
}

// ---------------------------------------------------------------------------
// Kernel 1: per-row threshold s_t (bf16-rounded inputs) + zero counters.
// ---------------------------------------------------------------------------
__global__ void prep_kernel(const float* __restrict__ P,
                            const float* __restrict__ Lab,
                            const int*   __restrict__ labels,
                            float* __restrict__ s_t,
                            int*   __restrict__ counts) {
    int gwave = (blockIdx.x * blockDim.x + threadIdx.x) >> 6;
    int lane  = threadIdx.x & 63;
    if (gwave >= B_ROWS) return;
    int t = labels[gwave];
    const float4* p4 = (const float4*)(P + (size_t)gwave * D_DIM);
    const float4* l4 = (const float4*)(Lab + (size_t)t * D_DIM);
    float4 a = p4[lane];
    float4 b = l4[lane];
    float sum = 0.f;
    sum += (float)(__bf16)a.x * (float)(__bf16)b.x;
    sum += (float)(__bf16)a.y * (float)(__bf16)b.y;
    sum += (float)(__bf16)a.z * (float)(__bf16)b.z;
    sum += (float)(__bf16)a.w * (float)(__bf16)b.w;
    #pragma unroll
    for (int m = 1; m < 64; m <<= 1) sum += __shfl_xor(sum, m, 64);
    if (lane == 0) {
        s_t[gwave]    = sum;
        counts[gwave] = 0;
    }
}

// ---------------------------------------------------------------------------
// Kernel 2 (fast): 128x256 tile, BK=64, 512 threads (8 waves, 2x4).
// global_load_lds(16B) staging with XOR chunk swizzle:
//   chunk ci (16B) of local row r stored at chunk slot ci ^ (r&7).
// ---------------------------------------------------------------------------
#define BM 128
#define BN 256
#define BK 64

__global__ __launch_bounds__(512)
void count_kernel_fast(const __hip_bfloat16* __restrict__ Pb,
                       const __hip_bfloat16* __restrict__ Lb,
                       const int*   __restrict__ labels,
                       const float* __restrict__ s_t,
                       int* __restrict__ counts) {
    __shared__ __align__(16) __bf16 As[BM * BK];   // 16 KB, swizzled
    __shared__ __align__(16) __bf16 Bs[BN * BK];   // 32 KB, swizzled

    const int Nbase = blockIdx.x * BN;
    const int Mbase = blockIdx.y * BM;
    const int tid   = threadIdx.x;
    const int lane  = tid & 63;
    const int wave  = tid >> 6;      // 0..7
    const int wm    = wave >> 2;     // 0..1 : 64-row half
    const int wn    = wave & 3;      // 0..3 : 64-col quarter
    const int quad  = lane >> 4;
    const int c     = lane & 15;

    f32x4 acc[4][4] = {};

    // Precompute staging global row/chunk for this thread (fixed across Kb).
    // A: positions p = wave*128 + j*64 + lane, j=0..1 (1024 chunks total)
    // B: positions p = wave*256 + j*64 + lane, j=0..3 (2048 chunks total)
    int a_row[2], a_ci[2], b_row[4], b_ci[4];
    #pragma unroll
    for (int j = 0; j < 2; ++j) {
        int p = wave * 128 + j * 64 + lane;
        a_row[j] = p >> 3;
        a_ci[j]  = (p & 7) ^ (a_row[j] & 7);
    }
    #pragma unroll
    for (int j = 0; j < 4; ++j) {
        int p = wave * 256 + j * 64 + lane;
        b_row[j] = p >> 3;
        b_ci[j]  = (p & 7) ^ (b_row[j] & 7);
    }

    for (int Kb = 0; Kb < D_DIM; Kb += BK) {
        #pragma unroll
        for (int j = 0; j < 2; ++j) {
            const __bf16* g = (const __bf16*)Pb +
                (size_t)(Mbase + a_row[j]) * D_DIM + Kb + a_ci[j] * 8;
            async16(g, &As[(wave * 128 + j * 64) * 8]);
        }
        #pragma unroll
        for (int j = 0; j < 4; ++j) {
            const __bf16* g = (const __bf16*)Lb +
                (size_t)(Nbase + b_row[j]) * D_DIM + Kb + b_ci[j] * 8;
            async16(g, &Bs[(wave * 256 + j * 64) * 8]);
        }
        __syncthreads();

        #pragma unroll
        for (int kb = 0; kb < 2; ++kb) {
            bf16x8 af[4], bf[4];
            #pragma unroll
            for (int mi = 0; mi < 4; ++mi) {
                int row = wm * 64 + mi * 16 + c;
                int sw  = (kb * 4 + quad) ^ (row & 7);
                af[mi] = *(const bf16x8*)&As[row * BK + sw * 8];
            }
            #pragma unroll
            for (int ni = 0; ni < 4; ++ni) {
                int col = wn * 64 + ni * 16 + c;
                int sw  = (kb * 4 + quad) ^ (col & 7);
                bf[ni] = *(const bf16x8*)&Bs[col * BK + sw * 8];
            }
            #pragma unroll
            for (int mi = 0; mi < 4; ++mi)
                #pragma unroll
                for (int ni = 0; ni < 4; ++ni)
                    acc[mi][ni] = __builtin_amdgcn_mfma_f32_16x16x32_bf16(
                        af[mi], bf[ni], acc[mi][ni], 0, 0, 0);
        }
        __syncthreads();
    }

    // Epilogue: C/D layout col = lane&15, row = quad*4 + reg  [m89/m91]
    #pragma unroll
    for (int mi = 0; mi < 4; ++mi) {
        int rowb = Mbase + wm * 64 + mi * 16 + quad * 4;
        #pragma unroll
        for (int r = 0; r < 4; ++r) {
            int   row = rowb + r;
            float st  = s_t[row];
            int   t   = labels[row];
            int   cnt = 0;
            #pragma unroll
            for (int ni = 0; ni < 4; ++ni) {
                int   n = Nbase + wn * 64 + ni * 16 + c;
                float s = acc[mi][ni][r];
                bool beat = (n < L_LABELS) && (n != t) &&
                            (s > st || (s == st && n < t));
                cnt += beat ? 1 : 0;
            }
            cnt += __shfl_xor(cnt, 1, 64);
            cnt += __shfl_xor(cnt, 2, 64);
            cnt += __shfl_xor(cnt, 4, 64);
            cnt += __shfl_xor(cnt, 8, 64);
            if (c == 0 && cnt) atomicAdd(&counts[row], cnt);
        }
    }
}

// ---------------------------------------------------------------------------
// Kernel 2 (fallback, R1 path): fp32 loads + in-kernel convert, 128x128 tile.
// Used only if ws_size is too small for the bf16 copies.
// ---------------------------------------------------------------------------
#define FBM 128
#define FBN 128
#define FBK 32
#define KPAD 40

__global__ __launch_bounds__(256)
void count_kernel_slow(const float* __restrict__ P,
                       const float* __restrict__ Lab,
                       const int*   __restrict__ labels,
                       const float* __restrict__ s_t,
                       int* __restrict__ counts) {
    __shared__ __align__(16) __bf16 As[FBM][KPAD];
    __shared__ __align__(16) __bf16 Bs[FBN][KPAD];

    const int Nbase = blockIdx.x * FBN;
    const int Mbase = blockIdx.y * FBM;
    const int tid  = threadIdx.x;
    const int lane = tid & 63;
    const int wave = tid >> 6;
    const int wm = wave >> 1;
    const int wn = wave & 1;
    const int quad = lane >> 4;
    const int c    = lane & 15;

    const int srow  = tid >> 1;
    const int skoff = (tid & 1) * 16;
    const int brow_g = min(Nbase + srow, L_LABELS - 1);

    f32x4 acc[4][4] = {};

    for (int Kb = 0; Kb < D_DIM; Kb += FBK) {
        const float* gA = P   + (size_t)(Mbase + srow) * D_DIM + Kb + skoff;
        const float* gB = Lab + (size_t)brow_g        * D_DIM + Kb + skoff;
        #pragma unroll
        for (int i = 0; i < 4; ++i) {
            float4 va = *(const float4*)(gA + i * 4);
            float4 vb = *(const float4*)(gB + i * 4);
            *(bf16x4*)&As[srow][skoff + i * 4] =
                (bf16x4){(__bf16)va.x, (__bf16)va.y, (__bf16)va.z, (__bf16)va.w};
            *(bf16x4*)&Bs[srow][skoff + i * 4] =
                (bf16x4){(__bf16)vb.x, (__bf16)vb.y, (__bf16)vb.z, (__bf16)vb.w};
        }
        __syncthreads();

        bf16x8 af[4], bf[4];
        #pragma unroll
        for (int mi = 0; mi < 4; ++mi)
            af[mi] = *(const bf16x8*)&As[wm * 64 + mi * 16 + c][quad * 8];
        #pragma unroll
        for (int ni = 0; ni < 4; ++ni)
            bf[ni] = *(const bf16x8*)&Bs[wn * 64 + ni * 16 + c][quad * 8];

        #pragma unroll
        for (int mi = 0; mi < 4; ++mi)
            #pragma unroll
            for (int ni = 0; ni < 4; ++ni)
                acc[mi][ni] = __builtin_amdgcn_mfma_f32_16x16x32_bf16(
                    af[mi], bf[ni], acc[mi][ni], 0, 0, 0);
        __syncthreads();
    }

    #pragma unroll
    for (int mi = 0; mi < 4; ++mi) {
        int rowb = Mbase + wm * 64 + mi * 16 + quad * 4;
        #pragma unroll
        for (int r = 0; r < 4; ++r) {
            int   row = rowb + r;
            float st  = s_t[row];
            int   t   = labels[row];
            int   cnt = 0;
            #pragma unroll
            for (int ni = 0; ni < 4; ++ni) {
                int   n = Nbase + wn * 64 + ni * 16 + c;
                float s = acc[mi][ni][r];
                bool beat = (n < L_LABELS) && (n != t) &&
                            (s > st || (s == st && n < t));
                cnt += beat ? 1 : 0;
            }
            cnt += __shfl_xor(cnt, 1, 64);
            cnt += __shfl_xor(cnt, 2, 64);
            cnt += __shfl_xor(cnt, 4, 64);
            cnt += __shfl_xor(cnt, 8, 64);
            if (c == 0 && cnt) atomicAdd(&counts[row], cnt);
        }
    }
}

// ---------------------------------------------------------------------------
// Kernel 3: accuracy = mean(counts[b] < TOPK)
// ---------------------------------------------------------------------------
__global__ void finalize_kernel(const int* __restrict__ counts,
                                float* __restrict__ out) {
    __shared__ int sdata[4];
    int tid = threadIdx.x;
    int local = 0;
    for (int i = tid; i < B_ROWS; i += 256)
        local += (counts[i] < TOPK) ? 1 : 0;
    #pragma unroll
    for (int m = 1; m < 64; m <<= 1) local += __shfl_xor(local, m, 64);
    if ((tid & 63) == 0) sdata[tid >> 6] = local;
    __syncthreads();
    if (tid == 0)
        out[0] = (float)(sdata[0] + sdata[1] + sdata[2] + sdata[3]) /
                 (float)B_ROWS;
}

extern "C" void kernel_launch(void* const* d_in, const int* in_sizes, int n_in,
                              void* d_out, int out_size, void* d_ws, size_t ws_size,
                              hipStream_t stream) {
    const float* P      = (const float*)d_in[0];
    const float* Lab    = (const float*)d_in[1];
    const int*   labels = (const int*)d_in[2];
    float* out = (float*)d_out;

    float* s_t    = (float*)d_ws;
    int*   counts = (int*)((char*)d_ws + 16384);

    prep_kernel<<<dim3(B_ROWS / 4), 256, 0, stream>>>(P, Lab, labels, s_t, counts);

    const size_t pb_off = 32768;
    const size_t lb_off = pb_off + (size_t)B_ROWS * D_DIM * 2;  // 2 MB
    const size_t need   = lb_off + (size_t)L_PAD * D_DIM * 2;   // ~51 MB

    if (ws_size >= need) {
        __hip_bfloat16* Pb = (__hip_bfloat16*)((char*)d_ws + pb_off);
        __hip_bfloat16* Lb = (__hip_bfloat16*)((char*)d_ws + lb_off);
        convertP_kernel<<<dim3((B_ROWS * D_DIM) / 2048), 256, 0, stream>>>(P, Pb);
        convertL_kernel<<<dim3(((size_t)L_PAD * D_DIM) / 2048), 256, 0, stream>>>(Lab, Lb);
        dim3 grid(L_PAD / BN, B_ROWS / BM);  // 391 x 32
        count_kernel_fast<<<grid, 512, 0, stream>>>(Pb, Lb, labels, s_t, counts);
    } else {
        dim3 grid((L_LABELS + FBN - 1) / FBN, B_ROWS / FBM);  // 782 x 32
        count_kernel_slow<<<grid, 256, 0, stream>>>(P, Lab, labels, s_t, counts);
    }

    finalize_kernel<<<1, 256, 0, stream>>>(counts, out);
}

// Round 3
// 910.725 us; speedup vs baseline: 1.3934x; 1.1503x over previous
//
#include <hip/hip_runtime.h>
#include <hip/hip_bf16.h>

#define B_ROWS   4096
#define L_LABELS 100000
#define L_PAD    100096   // 782 * 128, padded with zero rows
#define D_DIM    256
#define TOPK     5
#define NSLAB    782      // L_PAD / 128
#define NGROUP   8        // N-groups == XCD count

typedef __bf16 bf16x8 __attribute__((ext_vector_type(8)));
typedef __bf16 bf16x4 __attribute__((ext_vector_type(4)));
typedef float  f32x4  __attribute__((ext_vector_type(4)));

// ---------------------------------------------------------------------------
// fp32 -> bf16 converters
// ---------------------------------------------------------------------------
__global__ void convertP_kernel(const float* __restrict__ src,
                                __hip_bfloat16* __restrict__ dst) {
    size_t i = ((size_t)blockIdx.x * blockDim.x + threadIdx.x) * 8;
    float4 a = *(const float4*)(src + i);
    float4 b = *(const float4*)(src + i + 4);
    bf16x8 v = {(__bf16)a.x, (__bf16)a.y, (__bf16)a.z, (__bf16)a.w,
                (__bf16)b.x, (__bf16)b.y, (__bf16)b.z, (__bf16)b.w};
    *(bf16x8*)((__bf16*)dst + i) = v;
}

__global__ void convertL_kernel(const float* __restrict__ src,
                                __hip_bfloat16* __restrict__ dst) {
    size_t i = ((size_t)blockIdx.x * blockDim.x + threadIdx.x) * 8;
    bf16x8 v;
    if (i < (size_t)L_LABELS * D_DIM) {
        float4 a = *(const float4*)(src + i);
        float4 b = *(const float4*)(src + i + 4);
        v = (bf16x8){(__bf16)a.x, (__bf16)a.y, (__bf16)a.z, (__bf16)a.w,
                     (__bf16)b.x, (__bf16)b.y, (__bf16)b.z, (__bf16)b.w};
    } else {
        v = (bf16x8){(__bf16)0.f, (__bf16)0.f, (__bf16)0.f, (__bf16)0.f,
                     (__bf16)0.f, (__bf16)0.f, (__bf16)0.f, (__bf16)0.f};
    }
    *(bf16x8*)((__bf16*)dst + i) = v;
}

// ---------------------------------------------------------------------------
// Kernel 1: per-row threshold s_t (bf16-rounded inputs) + zero counters.
// ---------------------------------------------------------------------------
__global__ void prep_kernel(const float* __restrict__ P,
                            const float* __restrict__ Lab,
                            const int*   __restrict__ labels,
                            float* __restrict__ s_t,
                            int*   __restrict__ counts) {
    int gwave = (blockIdx.x * blockDim.x + threadIdx.x) >> 6;
    int lane  = threadIdx.x & 63;
    if (gwave >= B_ROWS) return;
    int t = labels[gwave];
    const float4* p4 = (const float4*)(P + (size_t)gwave * D_DIM);
    const float4* l4 = (const float4*)(Lab + (size_t)t * D_DIM);
    float4 a = p4[lane];
    float4 b = l4[lane];
    float sum = 0.f;
    sum += (float)(__bf16)a.x * (float)(__bf16)b.x;
    sum += (float)(__bf16)a.y * (float)(__bf16)b.y;
    sum += (float)(__bf16)a.z * (float)(__bf16)b.z;
    sum += (float)(__bf16)a.w * (float)(__bf16)b.w;
    #pragma unroll
    for (int m = 1; m < 64; m <<= 1) sum += __shfl_xor(sum, m, 64);
    if (lane == 0) {
        s_t[gwave]    = sum;
        counts[gwave] = 0;
    }
}

// ---------------------------------------------------------------------------
// Kernel 2 (v3): A-stationary / B-streaming count GEMM.
// Block = 512 threads (8 waves, 2 wm x 4 wn), tile 128 rows x full K=256.
// A staged to LDS once (64 KB); B slabs (128 labels x 256 K = 64 KB) stream
// through: register prefetch -> ds_write -> syncthreads -> MFMA -> raw
// s_barrier (no vmcnt drain; next slab's loads stay in flight).
// XOR chunk swizzle (16B chunk ci of row r at slot (ci&~7)|((ci^r)&7)) keeps
// both ds_write staging and ds_read_b128 frag reads conflict-free.
// Per-row beat counts accumulate in registers; atomics once at block end.
// ---------------------------------------------------------------------------
#define CBM 128
#define CBN 128

__global__ __launch_bounds__(512, 2)
void count_kernel_v3(const __hip_bfloat16* __restrict__ Pb,
                     const __hip_bfloat16* __restrict__ Lb,
                     const int*   __restrict__ labels,
                     const float* __restrict__ s_t,
                     int* __restrict__ counts) {
    __shared__ __align__(16) __bf16 As[CBM * D_DIM];   // 64 KB
    __shared__ __align__(16) __bf16 Bs[CBN * D_DIM];   // 64 KB

    const int group = blockIdx.x;          // 0..7  -> XCD via %8 heuristic
    const int Mbase = blockIdx.y * CBM;    // 0..31 M-tiles
    const int tid   = threadIdx.x;
    const int wave  = tid >> 6;            // 0..7
    const int lane  = tid & 63;
    const int wm    = wave >> 2;           // 0..1 : 64-row half
    const int wn    = wave & 3;            // 0..3 : 32-col quarter
    const int quad  = lane >> 4;           // 0..3
    const int cc    = lane & 15;           // 0..15

    // staging mapping: thread -> (row 0..127, chunk group 0/8/16/24)
    const int srow = tid >> 2;
    const int scig = (tid & 3) * 8;

    const int s0 = (group * NSLAB) / NGROUP;
    const int s1 = ((group + 1) * NSLAB) / NGROUP;

    // ---- stage A once (swizzled) ----
    {
        const uint4* gA = (const uint4*)(Pb + (size_t)(Mbase + srow) * D_DIM + scig * 8);
        uint4 areg[8];
        #pragma unroll
        for (int j = 0; j < 8; ++j) areg[j] = gA[j];
        #pragma unroll
        for (int j = 0; j < 8; ++j) {
            int ci  = scig + j;
            int sci = (ci & 24) | ((ci ^ srow) & 7);
            *(uint4*)&As[srow * D_DIM + sci * 8] = areg[j];
        }
    }

    // ---- preload per-row threshold/label for epilogue ----
    float sr[4][4];
    int   tr[4][4];
    #pragma unroll
    for (int mi = 0; mi < 4; ++mi)
        #pragma unroll
        for (int r = 0; r < 4; ++r) {
            int row = Mbase + wm * 64 + mi * 16 + quad * 4 + r;
            sr[mi][r] = s_t[row];
            tr[mi][r] = labels[row];
        }

    int cnt[4][4] = {};

    __syncthreads();   // A visible (drains everything; prefetch not yet issued)

    // ---- prefetch first B slab into registers ----
    uint4 breg[8];
    {
        const uint4* g = (const uint4*)(Lb + (size_t)(s0 * CBN + srow) * D_DIM + scig * 8);
        #pragma unroll
        for (int j = 0; j < 8; ++j) breg[j] = g[j];
    }

    for (int s = s0; s < s1; ++s) {
        // write prefetched slab to LDS (compiler inserts vmcnt wait here)
        #pragma unroll
        for (int j = 0; j < 8; ++j) {
            int ci  = scig + j;
            int sci = (ci & 24) | ((ci ^ srow) & 7);
            *(uint4*)&Bs[srow * D_DIM + sci * 8] = breg[j];
        }
        __syncthreads();   // B visible; vmcnt already 0 here

        // issue next slab's loads; they stay in flight through the MFMAs
        if (s + 1 < s1) {
            const uint4* g = (const uint4*)(Lb + (size_t)((s + 1) * CBN + srow) * D_DIM + scig * 8);
            #pragma unroll
            for (int j = 0; j < 8; ++j) breg[j] = g[j];
        }

        // ---- 512 MFMAs per block over full K=256 ----
        f32x4 acc[4][2] = {};
        #pragma unroll
        for (int kb = 0; kb < 8; ++kb) {
            bf16x8 af[4], bfr[2];
            #pragma unroll
            for (int mi = 0; mi < 4; ++mi) {
                int ar  = wm * 64 + mi * 16 + cc;
                int ci  = kb * 4 + quad;
                int sci = (ci & 24) | ((ci ^ ar) & 7);
                af[mi] = *(const bf16x8*)&As[ar * D_DIM + sci * 8];
            }
            #pragma unroll
            for (int ni = 0; ni < 2; ++ni) {
                int br  = wn * 32 + ni * 16 + cc;
                int ci  = kb * 4 + quad;
                int sci = (ci & 24) | ((ci ^ br) & 7);
                bfr[ni] = *(const bf16x8*)&Bs[br * D_DIM + sci * 8];
            }
            #pragma unroll
            for (int mi = 0; mi < 4; ++mi)
                #pragma unroll
                for (int ni = 0; ni < 2; ++ni)
                    acc[mi][ni] = __builtin_amdgcn_mfma_f32_16x16x32_bf16(
                        af[mi], bfr[ni], acc[mi][ni], 0, 0, 0);
        }

        // ---- epilogue: accumulate beat counts in registers ----
        int nb = s * CBN + wn * 32;
        #pragma unroll
        for (int mi = 0; mi < 4; ++mi)
            #pragma unroll
            for (int ni = 0; ni < 2; ++ni)
                #pragma unroll
                for (int r = 0; r < 4; ++r) {
                    float sv = acc[mi][ni][r];
                    int   n  = nb + ni * 16 + cc;
                    bool beat = (n < L_LABELS) && (n != tr[mi][r]) &&
                                (sv > sr[mi][r] ||
                                 (sv == sr[mi][r] && n < tr[mi][r]));
                    cnt[mi][r] += beat ? 1 : 0;
                }

        // raw barrier: all waves done reading Bs; prefetch stays in flight
        asm volatile("s_barrier" ::: "memory");
    }

    // ---- final reduction: sum over cc lanes, one atomic per row-quarter ----
    #pragma unroll
    for (int mi = 0; mi < 4; ++mi)
        #pragma unroll
        for (int r = 0; r < 4; ++r) {
            int v = cnt[mi][r];
            v += __shfl_xor(v, 1, 64);
            v += __shfl_xor(v, 2, 64);
            v += __shfl_xor(v, 4, 64);
            v += __shfl_xor(v, 8, 64);
            if (cc == 0) {
                int row = Mbase + wm * 64 + mi * 16 + quad * 4 + r;
                atomicAdd(&counts[row], v);
            }
        }
}

// ---------------------------------------------------------------------------
// Kernel 2 (fallback, R1 path) — used only if ws too small for bf16 copies.
// ---------------------------------------------------------------------------
#define FBM 128
#define FBN 128
#define FBK 32
#define KPAD 40

__global__ __launch_bounds__(256)
void count_kernel_slow(const float* __restrict__ P,
                       const float* __restrict__ Lab,
                       const int*   __restrict__ labels,
                       const float* __restrict__ s_t,
                       int* __restrict__ counts) {
    __shared__ __align__(16) __bf16 As[FBM][KPAD];
    __shared__ __align__(16) __bf16 Bs[FBN][KPAD];

    const int Nbase = blockIdx.x * FBN;
    const int Mbase = blockIdx.y * FBM;
    const int tid  = threadIdx.x;
    const int lane = tid & 63;
    const int wave = tid >> 6;
    const int wm = wave >> 1;
    const int wn = wave & 1;
    const int quad = lane >> 4;
    const int c    = lane & 15;

    const int srow  = tid >> 1;
    const int skoff = (tid & 1) * 16;
    const int brow_g = min(Nbase + srow, L_LABELS - 1);

    f32x4 acc[4][4] = {};

    for (int Kb = 0; Kb < D_DIM; Kb += FBK) {
        const float* gA = P   + (size_t)(Mbase + srow) * D_DIM + Kb + skoff;
        const float* gB = Lab + (size_t)brow_g        * D_DIM + Kb + skoff;
        #pragma unroll
        for (int i = 0; i < 4; ++i) {
            float4 va = *(const float4*)(gA + i * 4);
            float4 vb = *(const float4*)(gB + i * 4);
            *(bf16x4*)&As[srow][skoff + i * 4] =
                (bf16x4){(__bf16)va.x, (__bf16)va.y, (__bf16)va.z, (__bf16)va.w};
            *(bf16x4*)&Bs[srow][skoff + i * 4] =
                (bf16x4){(__bf16)vb.x, (__bf16)vb.y, (__bf16)vb.z, (__bf16)vb.w};
        }
        __syncthreads();

        bf16x8 af[4], bf[4];
        #pragma unroll
        for (int mi = 0; mi < 4; ++mi)
            af[mi] = *(const bf16x8*)&As[wm * 64 + mi * 16 + c][quad * 8];
        #pragma unroll
        for (int ni = 0; ni < 4; ++ni)
            bf[ni] = *(const bf16x8*)&Bs[wn * 64 + ni * 16 + c][quad * 8];

        #pragma unroll
        for (int mi = 0; mi < 4; ++mi)
            #pragma unroll
            for (int ni = 0; ni < 4; ++ni)
                acc[mi][ni] = __builtin_amdgcn_mfma_f32_16x16x32_bf16(
                    af[mi], bf[ni], acc[mi][ni], 0, 0, 0);
        __syncthreads();
    }

    #pragma unroll
    for (int mi = 0; mi < 4; ++mi) {
        int rowb = Mbase + wm * 64 + mi * 16 + quad * 4;
        #pragma unroll
        for (int r = 0; r < 4; ++r) {
            int   row = rowb + r;
            float st  = s_t[row];
            int   t   = labels[row];
            int   cnt = 0;
            #pragma unroll
            for (int ni = 0; ni < 4; ++ni) {
                int   n = Nbase + wn * 64 + ni * 16 + c;
                float s = acc[mi][ni][r];
                bool beat = (n < L_LABELS) && (n != t) &&
                            (s > st || (s == st && n < t));
                cnt += beat ? 1 : 0;
            }
            cnt += __shfl_xor(cnt, 1, 64);
            cnt += __shfl_xor(cnt, 2, 64);
            cnt += __shfl_xor(cnt, 4, 64);
            cnt += __shfl_xor(cnt, 8, 64);
            if (c == 0 && cnt) atomicAdd(&counts[row], cnt);
        }
    }
}

// ---------------------------------------------------------------------------
// Kernel 3: accuracy = mean(counts[b] < TOPK)
// ---------------------------------------------------------------------------
__global__ void finalize_kernel(const int* __restrict__ counts,
                                float* __restrict__ out) {
    __shared__ int sdata[4];
    int tid = threadIdx.x;
    int local = 0;
    for (int i = tid; i < B_ROWS; i += 256)
        local += (counts[i] < TOPK) ? 1 : 0;
    #pragma unroll
    for (int m = 1; m < 64; m <<= 1) local += __shfl_xor(local, m, 64);
    if ((tid & 63) == 0) sdata[tid >> 6] = local;
    __syncthreads();
    if (tid == 0)
        out[0] = (float)(sdata[0] + sdata[1] + sdata[2] + sdata[3]) /
                 (float)B_ROWS;
}

extern "C" void kernel_launch(void* const* d_in, const int* in_sizes, int n_in,
                              void* d_out, int out_size, void* d_ws, size_t ws_size,
                              hipStream_t stream) {
    const float* P      = (const float*)d_in[0];
    const float* Lab    = (const float*)d_in[1];
    const int*   labels = (const int*)d_in[2];
    float* out = (float*)d_out;

    float* s_t    = (float*)d_ws;
    int*   counts = (int*)((char*)d_ws + 16384);

    prep_kernel<<<dim3(B_ROWS / 4), 256, 0, stream>>>(P, Lab, labels, s_t, counts);

    const size_t pb_off = 32768;
    const size_t lb_off = pb_off + (size_t)B_ROWS * D_DIM * 2;  // 2 MB
    const size_t need   = lb_off + (size_t)L_PAD * D_DIM * 2;   // ~51 MB

    if (ws_size >= need) {
        __hip_bfloat16* Pb = (__hip_bfloat16*)((char*)d_ws + pb_off);
        __hip_bfloat16* Lb = (__hip_bfloat16*)((char*)d_ws + lb_off);
        convertP_kernel<<<dim3((B_ROWS * D_DIM) / 2048), 256, 0, stream>>>(P, Pb);
        convertL_kernel<<<dim3(((size_t)L_PAD * D_DIM) / 2048), 256, 0, stream>>>(Lab, Lb);
        count_kernel_v3<<<dim3(NGROUP, B_ROWS / CBM), 512, 0, stream>>>(
            Pb, Lb, labels, s_t, counts);
    } else {
        dim3 grid((L_LABELS + FBN - 1) / FBN, B_ROWS / FBM);
        count_kernel_slow<<<grid, 256, 0, stream>>>(P, Lab, labels, s_t, counts);
    }

    finalize_kernel<<<1, 256, 0, stream>>>(counts, out);
}

// Round 4
// 496.946 us; speedup vs baseline: 2.5536x; 1.8326x over previous
//
#include <hip/hip_runtime.h>
#include <hip/hip_bf16.h>

#define B_ROWS   4096
#define L_LABELS 100000
#define L_PAD    100032   // 1563 * 64, padded with zero rows
#define PADROWS  32       // L_PAD - L_LABELS
#define D_DIM    256
#define TOPK     5
#define SLABN    64       // labels per slab
#define NSLAB    1563     // L_PAD / SLABN
#define NGROUP   8        // N-groups == XCD count

typedef __bf16 bf16x8 __attribute__((ext_vector_type(8)));
typedef __bf16 bf16x4 __attribute__((ext_vector_type(4)));
typedef float  f32x4  __attribute__((ext_vector_type(4)));

__device__ __forceinline__ void async16(const void* g, void* l) {
    __builtin_amdgcn_global_load_lds(
        (const __attribute__((address_space(1))) unsigned int*)g,
        (__attribute__((address_space(3))) unsigned int*)l,
        16, 0, 0);
}

// ---------------------------------------------------------------------------
// fp32 -> bf16 converters
// ---------------------------------------------------------------------------
__global__ void convertP_kernel(const float* __restrict__ src,
                                __hip_bfloat16* __restrict__ dst) {
    size_t i = ((size_t)blockIdx.x * blockDim.x + threadIdx.x) * 8;
    float4 a = *(const float4*)(src + i);
    float4 b = *(const float4*)(src + i + 4);
    bf16x8 v = {(__bf16)a.x, (__bf16)a.y, (__bf16)a.z, (__bf16)a.w,
                (__bf16)b.x, (__bf16)b.y, (__bf16)b.z, (__bf16)b.w};
    *(bf16x8*)((__bf16*)dst + i) = v;
}

__global__ void convertL_kernel(const float* __restrict__ src,
                                __hip_bfloat16* __restrict__ dst) {
    size_t i = ((size_t)blockIdx.x * blockDim.x + threadIdx.x) * 8;
    bf16x8 v;
    if (i < (size_t)L_LABELS * D_DIM) {
        float4 a = *(const float4*)(src + i);
        float4 b = *(const float4*)(src + i + 4);
        v = (bf16x8){(__bf16)a.x, (__bf16)a.y, (__bf16)a.z, (__bf16)a.w,
                     (__bf16)b.x, (__bf16)b.y, (__bf16)b.z, (__bf16)b.w};
    } else {
        v = (bf16x8){(__bf16)0.f, (__bf16)0.f, (__bf16)0.f, (__bf16)0.f,
                     (__bf16)0.f, (__bf16)0.f, (__bf16)0.f, (__bf16)0.f};
    }
    *(bf16x8*)((__bf16*)dst + i) = v;
}

// ---------------------------------------------------------------------------
// Kernel 1: per-row threshold s_t (bf16-rounded inputs) + zero counters.
// ---------------------------------------------------------------------------
__global__ void prep_kernel(const float* __restrict__ P,
                            const float* __restrict__ Lab,
                            const int*   __restrict__ labels,
                            float* __restrict__ s_t,
                            int*   __restrict__ counts) {
    int gwave = (blockIdx.x * blockDim.x + threadIdx.x) >> 6;
    int lane  = threadIdx.x & 63;
    if (gwave >= B_ROWS) return;
    int t = labels[gwave];
    const float4* p4 = (const float4*)(P + (size_t)gwave * D_DIM);
    const float4* l4 = (const float4*)(Lab + (size_t)t * D_DIM);
    float4 a = p4[lane];
    float4 b = l4[lane];
    float sum = 0.f;
    sum += (float)(__bf16)a.x * (float)(__bf16)b.x;
    sum += (float)(__bf16)a.y * (float)(__bf16)b.y;
    sum += (float)(__bf16)a.z * (float)(__bf16)b.z;
    sum += (float)(__bf16)a.w * (float)(__bf16)b.w;
    #pragma unroll
    for (int m = 1; m < 64; m <<= 1) sum += __shfl_xor(sum, m, 64);
    if (lane == 0) {
        s_t[gwave]    = sum;
        counts[gwave] = 0;
    }
}

// ---------------------------------------------------------------------------
// Kernel 2 (v4): A-in-registers / B-DMA-streaming count GEMM.
// Block = 512 thr (8 waves: 2 wm x 4 wn). M-tile 128 x full K=256 stationary
// in registers (af[4][8], 128 VGPR/lane). B: 64-label slabs double-buffered
// in LDS via global_load_lds (no VGPR staging -> no spills).
// Global-side XOR chunk swizzle: LDS slot (row,qc) holds global chunk
// (qc&24)|((qc^row)&7)  -> ds_read_b128 frag reads hit all 8 bank groups.
// Pad labels contribute exactly +0.0f; corrected in finalize.
// ---------------------------------------------------------------------------
#define CBM 128

__global__ __launch_bounds__(512, 2)
void count_kernel_v4(const __hip_bfloat16* __restrict__ Pb,
                     const __hip_bfloat16* __restrict__ Lb,
                     const int*   __restrict__ labels,
                     const float* __restrict__ s_t,
                     int* __restrict__ counts) {
    __shared__ __align__(16) __bf16 Bs[2 * SLABN * D_DIM];   // 2 x 32 KB

    const int group = blockIdx.x;          // 0..7 -> XCD via %8 dispatch
    const int Mbase = blockIdx.y * CBM;
    const int tid   = threadIdx.x;
    const int wave  = tid >> 6;            // 0..7
    const int lane  = tid & 63;
    const int wm    = wave >> 2;           // 0..1 : 64-row half
    const int wn    = wave & 3;            // 0..3 : 16-label quarter
    const int quad  = lane >> 4;           // 0..3
    const int cc    = lane & 15;           // 0..15

    const int s0 = (group * NSLAB) / NGROUP;
    const int s1 = ((group + 1) * NSLAB) / NGROUP;

    // per-thread DMA source offsets (bytes within a slab) + LDS wave bases
    int dma_off[4];
    #pragma unroll
    for (int j = 0; j < 4; ++j) {
        int q   = j * 512 + tid;       // chunk slot 0..2047
        int row = q >> 5;              // label row 0..63
        int qc  = q & 31;              // chunk col in row
        int gc  = (qc & 24) | ((qc ^ row) & 7);
        dma_off[j] = row * 512 + gc * 16;
    }

    // ---- issue DMA for first slab into buffer 0 ----
    {
        const char* gbase = (const char*)Lb + (size_t)s0 * (SLABN * D_DIM * 2);
        #pragma unroll
        for (int j = 0; j < 4; ++j)
            async16(gbase + dma_off[j],
                    (char*)Bs + (size_t)(j * 512 + wave * 64) * 16);
    }

    // ---- load stationary A fragments: 64 rows x K=256 per wave ----
    bf16x8 af[4][8];
    #pragma unroll
    for (int mi = 0; mi < 4; ++mi) {
        int row = Mbase + wm * 64 + mi * 16 + cc;
        const __bf16* ap = (const __bf16*)Pb + (size_t)row * D_DIM + quad * 8;
        #pragma unroll
        for (int kb = 0; kb < 8; ++kb)
            af[mi][kb] = *(const bf16x8*)(ap + kb * 32);
    }

    // ---- per-row threshold / label (C/D rows: quad*4 + r) ----
    float sr[4][4];
    int   tr[4][4];
    #pragma unroll
    for (int mi = 0; mi < 4; ++mi)
        #pragma unroll
        for (int r = 0; r < 4; ++r) {
            int row = Mbase + wm * 64 + mi * 16 + quad * 4 + r;
            sr[mi][r] = s_t[row];
            tr[mi][r] = labels[row];
        }

    int cnt[4][4] = {};

    for (int s = s0, it = 0; s < s1; ++s, ++it) {
        __syncthreads();   // waits current slab's DMA (vmcnt 0) + buffer reuse

        // issue next slab's DMA into the other buffer; stays in flight
        if (s + 1 < s1) {
            const char* gbase = (const char*)Lb + (size_t)(s + 1) * (SLABN * D_DIM * 2);
            char* lbase = (char*)Bs + (size_t)((~it & 1)) * (SLABN * D_DIM * 2);
            #pragma unroll
            for (int j = 0; j < 4; ++j)
                async16(gbase + dma_off[j],
                        lbase + (size_t)(j * 512 + wave * 64) * 16);
        }

        const __bf16* bp = Bs + (size_t)(it & 1) * (SLABN * D_DIM);

        f32x4 acc[4] = {};
        #pragma unroll
        for (int kb = 0; kb < 8; ++kb) {
            int ci = kb * 4 + quad;
            int qc = (ci & 24) | ((ci ^ cc) & 7);   // col&7 == cc&7
            bf16x8 b = *(const bf16x8*)&bp[(wn * 16 + cc) * D_DIM + qc * 8];
            #pragma unroll
            for (int mi = 0; mi < 4; ++mi)
                acc[mi] = __builtin_amdgcn_mfma_f32_16x16x32_bf16(
                    af[mi][kb], b, acc[mi], 0, 0, 0);
        }

        // epilogue: accumulate beat counts in registers
        int nb = s * SLABN + wn * 16;
        int n  = nb + cc;
        #pragma unroll
        for (int mi = 0; mi < 4; ++mi)
            #pragma unroll
            for (int r = 0; r < 4; ++r) {
                float sv = acc[mi][r];
                bool beat = (n != tr[mi][r]) &&
                            (sv > sr[mi][r] ||
                             (sv == sr[mi][r] && n < tr[mi][r]));
                cnt[mi][r] += beat ? 1 : 0;
            }
    }

    // ---- reduce over the 16 cc lanes, one atomic per (wave, quad, mi, r) ----
    #pragma unroll
    for (int mi = 0; mi < 4; ++mi)
        #pragma unroll
        for (int r = 0; r < 4; ++r) {
            int v = cnt[mi][r];
            v += __shfl_xor(v, 1, 64);
            v += __shfl_xor(v, 2, 64);
            v += __shfl_xor(v, 4, 64);
            v += __shfl_xor(v, 8, 64);
            if (cc == 0) {
                int row = Mbase + wm * 64 + mi * 16 + quad * 4 + r;
                atomicAdd(&counts[row], v);
            }
        }
}

// ---------------------------------------------------------------------------
// Kernel 2 (fallback, R1 path) — only if ws too small for bf16 copies.
// ---------------------------------------------------------------------------
#define FBM 128
#define FBN 128
#define FBK 32
#define KPAD 40

__global__ __launch_bounds__(256)
void count_kernel_slow(const float* __restrict__ P,
                       const float* __restrict__ Lab,
                       const int*   __restrict__ labels,
                       const float* __restrict__ s_t,
                       int* __restrict__ counts) {
    __shared__ __align__(16) __bf16 As[FBM][KPAD];
    __shared__ __align__(16) __bf16 Bs[FBN][KPAD];

    const int Nbase = blockIdx.x * FBN;
    const int Mbase = blockIdx.y * FBM;
    const int tid  = threadIdx.x;
    const int lane = tid & 63;
    const int wave = tid >> 6;
    const int wm = wave >> 1;
    const int wn = wave & 1;
    const int quad = lane >> 4;
    const int c    = lane & 15;

    const int srow  = tid >> 1;
    const int skoff = (tid & 1) * 16;
    const int brow_g = min(Nbase + srow, L_LABELS - 1);

    f32x4 acc[4][4] = {};

    for (int Kb = 0; Kb < D_DIM; Kb += FBK) {
        const float* gA = P   + (size_t)(Mbase + srow) * D_DIM + Kb + skoff;
        const float* gB = Lab + (size_t)brow_g        * D_DIM + Kb + skoff;
        #pragma unroll
        for (int i = 0; i < 4; ++i) {
            float4 va = *(const float4*)(gA + i * 4);
            float4 vb = *(const float4*)(gB + i * 4);
            *(bf16x4*)&As[srow][skoff + i * 4] =
                (bf16x4){(__bf16)va.x, (__bf16)va.y, (__bf16)va.z, (__bf16)va.w};
            *(bf16x4*)&Bs[srow][skoff + i * 4] =
                (bf16x4){(__bf16)vb.x, (__bf16)vb.y, (__bf16)vb.z, (__bf16)vb.w};
        }
        __syncthreads();

        bf16x8 afr[4], bfr[4];
        #pragma unroll
        for (int mi = 0; mi < 4; ++mi)
            afr[mi] = *(const bf16x8*)&As[wm * 64 + mi * 16 + c][quad * 8];
        #pragma unroll
        for (int ni = 0; ni < 4; ++ni)
            bfr[ni] = *(const bf16x8*)&Bs[wn * 64 + ni * 16 + c][quad * 8];

        #pragma unroll
        for (int mi = 0; mi < 4; ++mi)
            #pragma unroll
            for (int ni = 0; ni < 4; ++ni)
                acc[mi][ni] = __builtin_amdgcn_mfma_f32_16x16x32_bf16(
                    afr[mi], bfr[ni], acc[mi][ni], 0, 0, 0);
        __syncthreads();
    }

    #pragma unroll
    for (int mi = 0; mi < 4; ++mi) {
        int rowb = Mbase + wm * 64 + mi * 16 + quad * 4;
        #pragma unroll
        for (int r = 0; r < 4; ++r) {
            int   row = rowb + r;
            float st  = s_t[row];
            int   t   = labels[row];
            int   cnt = 0;
            #pragma unroll
            for (int ni = 0; ni < 4; ++ni) {
                int   n = Nbase + wn * 64 + ni * 16 + c;
                float s = acc[mi][ni][r];
                bool beat = (n < L_LABELS) && (n != t) &&
                            (s > st || (s == st && n < t));
                cnt += beat ? 1 : 0;
            }
            cnt += __shfl_xor(cnt, 1, 64);
            cnt += __shfl_xor(cnt, 2, 64);
            cnt += __shfl_xor(cnt, 4, 64);
            cnt += __shfl_xor(cnt, 8, 64);
            if (c == 0 && cnt) atomicAdd(&counts[row], cnt);
        }
    }
}

// ---------------------------------------------------------------------------
// Kernel 3: accuracy = mean(adjusted_counts[b] < TOPK).
// Pad labels (zero rows) contributed exactly (0.0f > s_t) beats x PADROWS
// (only in the fast path; correction is 0 when counts came from slow path
// because slow path bounds-checks). We pass a flag.
// ---------------------------------------------------------------------------
__global__ void finalize_kernel(const int* __restrict__ counts,
                                const float* __restrict__ s_t,
                                float* __restrict__ out,
                                int pad_correct) {
    __shared__ int sdata[4];
    int tid = threadIdx.x;
    int local = 0;
    for (int i = tid; i < B_ROWS; i += 256) {
        int c = counts[i];
        if (pad_correct && s_t[i] < 0.0f) c -= PADROWS;
        local += (c < TOPK) ? 1 : 0;
    }
    #pragma unroll
    for (int m = 1; m < 64; m <<= 1) local += __shfl_xor(local, m, 64);
    if ((tid & 63) == 0) sdata[tid >> 6] = local;
    __syncthreads();
    if (tid == 0)
        out[0] = (float)(sdata[0] + sdata[1] + sdata[2] + sdata[3]) /
                 (float)B_ROWS;
}

extern "C" void kernel_launch(void* const* d_in, const int* in_sizes, int n_in,
                              void* d_out, int out_size, void* d_ws, size_t ws_size,
                              hipStream_t stream) {
    const float* P      = (const float*)d_in[0];
    const float* Lab    = (const float*)d_in[1];
    const int*   labels = (const int*)d_in[2];
    float* out = (float*)d_out;

    float* s_t    = (float*)d_ws;
    int*   counts = (int*)((char*)d_ws + 16384);

    prep_kernel<<<dim3(B_ROWS / 4), 256, 0, stream>>>(P, Lab, labels, s_t, counts);

    const size_t pb_off = 32768;
    const size_t lb_off = pb_off + (size_t)B_ROWS * D_DIM * 2;  // 2 MB
    const size_t need   = lb_off + (size_t)L_PAD * D_DIM * 2;   // ~51 MB

    int fast = (ws_size >= need) ? 1 : 0;
    if (fast) {
        __hip_bfloat16* Pb = (__hip_bfloat16*)((char*)d_ws + pb_off);
        __hip_bfloat16* Lb = (__hip_bfloat16*)((char*)d_ws + lb_off);
        convertP_kernel<<<dim3((B_ROWS * D_DIM) / 2048), 256, 0, stream>>>(P, Pb);
        convertL_kernel<<<dim3(((size_t)L_PAD * D_DIM) / 2048), 256, 0, stream>>>(Lab, Lb);
        count_kernel_v4<<<dim3(NGROUP, B_ROWS / CBM), 512, 0, stream>>>(
            Pb, Lb, labels, s_t, counts);
    } else {
        dim3 grid((L_LABELS + FBN - 1) / FBN, B_ROWS / FBM);
        count_kernel_slow<<<grid, 256, 0, stream>>>(P, Lab, labels, s_t, counts);
    }

    finalize_kernel<<<1, 256, 0, stream>>>(counts, s_t, out, fast);
}